// Round 13
// baseline (473.843 us; speedup 1.0000x reference)
//
#include <hip/hip_runtime.h>
#include <hip/hip_bf16.h>
#include <stdint.h>

#define B_Q   1024
#define C_K   262144
#define D_DIM 512
#define V_DIM 512
#define K_TOP 8
#define BM 128
#define BN 128
#define BK 64
#define NT (C_K/BN)    /* 2048 n-tiles */
#define MT (B_Q/BM)    /* 8 m-tiles */
#define NKT (D_DIM/BK) /* 8 K-tiles per nt-tile */
#define TPB 32         /* nt-tiles per persistent block (grid 512, 2/CU) */
#define CAP 2048       /* candidate list capacity per query (E[n]~293) */
#define QS 8.0f        /* per-side fp8 pre-scale */
#define TAU_S 8.64f    /* 64 * 0.135 (z=3.05); rescore window 64 -> 13-sigma margin */
#define RWIN 64        /* exact-rescore window */

typedef float f32x4 __attribute__((ext_vector_type(4)));
typedef __attribute__((address_space(3))) unsigned char lds_uchar;
typedef __attribute__((address_space(1))) const unsigned char gbl_uchar;

// One wave per row: L2-normalize (fp32 norm), scale by QS, emit fp8 e4m3.
// Block 0 additionally zeroes the candidate counters (when cnt != nullptr).
__global__ __launch_bounds__(256) void nrm_rows(const float* __restrict__ in,
                                                uint8_t* __restrict__ out,
                                                int nrows, int* cnt, int ncnt){
  if (cnt != nullptr && blockIdx.x == 0){
    for (int i = threadIdx.x; i < ncnt; i += 256) cnt[i] = 0;
  }
  int row  = blockIdx.x*4 + (threadIdx.x>>6);
  int lane = threadIdx.x & 63;
  if (row >= nrows) return;
  const float4* r4 = (const float4*)(in + (size_t)row*D_DIM);
  float4 a = r4[lane*2], b = r4[lane*2+1];
  float ss = a.x*a.x+a.y*a.y+a.z*a.z+a.w*a.w
           + b.x*b.x+b.y*b.y+b.z*b.z+b.w*b.w;
  #pragma unroll
  for (int off=32; off>0; off>>=1) ss += __shfl_xor(ss, off);
  float rn = QS / fmaxf(sqrtf(ss), 1e-12f);
  int w0 = __builtin_amdgcn_cvt_pk_fp8_f32(a.x*rn, a.y*rn, 0,  false);
  w0     = __builtin_amdgcn_cvt_pk_fp8_f32(a.z*rn, a.w*rn, w0, true);
  int w1 = __builtin_amdgcn_cvt_pk_fp8_f32(b.x*rn, b.y*rn, 0,  false);
  w1     = __builtin_amdgcn_cvt_pk_fp8_f32(b.z*rn, b.w*rn, w1, true);
  ((uint2*)(out + (size_t)row*D_DIM))[lane] = make_uint2((unsigned)w0, (unsigned)w1);
}

// PERSISTENT 128x128 fp8 MFMA GEMM (scores scaled by 64): grid=512 = 2
// blocks/CU; 8 waves (2Mx4N), each owns 64x32; LDS 2 x 16KB double buffer.
// K-step = 2 barriers only: head {STAGE(kt+1) -> vmcnt(2) -> publish barrier}
// (R11-proven counting) and end-of-tile {lgkmcnt(0)+sched_barrier -> barrier}
// (a wave must not pass with ds_reads in flight: next head restages the
// buffer it was reading; rule #18 guards the hoist). NO mid barrier, NO mid
// pins — reads/MFMAs are wave-private, compiler emits counted lgkmcnt to
// interleave ds_read returns with MFMA issue (m97/m141).
// Swizzle: 16B unit u' = u ^ ((row>>1)&3), linear LDS dest +
// inverse-swizzled global source. Epilogue per nt-tile = threshold filter +
// rare atomic append.
__global__ __launch_bounds__(512, 4) void gemm_topk(const uint8_t* __restrict__ qn,
                                                    const uint8_t* __restrict__ kn,
                                                    int* __restrict__ cnt,
                                                    float2* __restrict__ cand){
  extern __shared__ __align__(16) unsigned char smem[];   // 32768 bytes

  const int tid  = threadIdx.x;
  const int lane = tid & 63;
  const int w    = tid >> 6;           // 0..7
  const int wm = w >> 2, wn = w & 3;   // 2 x 4 wave grid: 128 rows x 128 cols

  const unsigned bid = blockIdx.x;     // 0..511
  const int xcd  = bid & 7;
  const int s    = bid >> 3;           // 0..63
  const int mt   = s & 7;              // 8 m-tiles
  const int nt0  = xcd*256 + (s >> 3)*TPB;   // group walks nt0..nt0+31

  f32x4 zero4 = {0.f,0.f,0.f,0.f};
  f32x4 acc[4][2];
  #pragma unroll
  for (int a=0;a<4;a++)
    #pragma unroll
    for (int b=0;b<2;b++) acc[a][b] = zero4;

  const uint8_t* ab  = qn + (size_t)mt*BM*D_DIM;
  const uint8_t* bb0 = kn + (size_t)nt0*BN*D_DIM;

  // staging map: thread t covers 16B unit t of A and unit t of B (512 each).
  // unit n -> row n>>2, dest-unit n&3; source unit = (n&3) ^ ((row>>1)&3).
  const int srow = tid >> 2;                                  // 0..127
  const unsigned ssw = (unsigned)(((tid & 3) ^ ((srow >> 1) & 3)) << 4);
  const uint8_t* aptr = ab  + (size_t)srow*D_DIM + ssw;       // += 64/K-tile
  const uint8_t* bptr = bb0 + (size_t)srow*D_DIM + ssw;
  const unsigned dst0 = (unsigned)tid*16u;

  #define STAGE_KT(buf_) do{                                                    \
    const unsigned cb_ = (unsigned)(buf_)*16384u;                                \
    __builtin_amdgcn_global_load_lds((gbl_uchar*)(aptr),                         \
        (lds_uchar*)(smem + cb_ + dst0), 16, 0, 0);                              \
    __builtin_amdgcn_global_load_lds((gbl_uchar*)(bptr),                         \
        (lds_uchar*)(smem + cb_ + 8192u + dst0), 16, 0, 0);                      \
  }while(0)

  // frag byte offset for (row_, slot s_): s_ = ks*4 + (lane>>4), 8B granule
  #define FOFF(row_, s_) \
    ((unsigned)((row_)*64 + (((((s_)>>1) ^ (((row_)>>1)&3))<<4) | (((s_)&1)<<3))))

  // 4 ds_read_b64: A-frags (all 4 m) for one ks into dst_[4]
  #define LOADA(dst_, cbase_, ks_) do{                                           \
    const int s_ = (ks_)*4 + (lane>>4);                                          \
    _Pragma("unroll")                                                            \
    for (int f=0; f<4; f++){                                                     \
      const int row_ = wm*64 + f*16 + (lane&15);                                 \
      dst_[f] = *(const unsigned long long*)(smem + (cbase_) + FOFF(row_, s_));  \
    }                                                                            \
  }while(0)

  // 2 ds_read_b64: B-frags (both n) for one ks into dst_[2]
  #define LOADB(dst_, cbase_, ks_) do{                                           \
    const int s_ = (ks_)*4 + (lane>>4);                                          \
    _Pragma("unroll")                                                            \
    for (int g=0; g<2; g++){                                                     \
      const int row_ = wn*32 + g*16 + (lane&15);                                 \
      dst_[g] = *(const unsigned long long*)(smem + (cbase_) + 8192u             \
                                             + FOFF(row_, s_));                  \
    }                                                                            \
  }while(0)

  // 8 independent MFMA: all 4m x 2n, one ks
  #define MFMAP(af_, bf_)                                                        \
    _Pragma("unroll")                                                            \
    for (int f=0; f<4; f++)                                                      \
      _Pragma("unroll")                                                          \
      for (int g=0; g<2; g++)                                                    \
        acc[f][g] = __builtin_amdgcn_mfma_f32_16x16x32_fp8_fp8(                  \
            (long long)af_[f], (long long)bf_[g], acc[f][g], 0, 0, 0);

  STAGE_KT(0);
  aptr += 64; bptr += 64;                // -> K-tile 1 data
  __syncthreads();                       // prologue

  for (int kt=0; kt<TPB*NKT; kt++){      // 256 K-tile steps, continuous
    const unsigned cbase = (unsigned)(kt&1)*16384u;
    unsigned long long a0[4], a1[4], b0[2], b1[2];

    // loop head (proven): issue STAGE(kt+1), then counted wait — STAGE(kt)'s
    // loads are now older than the 2 newest => landed. Then publish.
    if (kt < TPB*NKT-1){
      STAGE_KT((kt+1)&1);
      const bool wrap = ((kt+1)&7) == 7;   // advance to kt+2's data
      aptr += wrap ? -(7*64) : 64;
      bptr += wrap ? ((size_t)BN*D_DIM - 7*64) : 64;
      asm volatile("s_waitcnt vmcnt(2)" ::: "memory");
    } else {
      asm volatile("s_waitcnt vmcnt(0)" ::: "memory");
    }
    __builtin_amdgcn_sched_barrier(0);
    __builtin_amdgcn_s_barrier();        // publish buffer kt (vmcnt per-wave)

    // body: 12 reads then 16 MFMA — wave-private, compiler-scheduled
    // (counted lgkmcnt interleaves read returns with MFMA issue)
    LOADB(b0, cbase, 0);
    LOADA(a0, cbase, 0);
    LOADB(b1, cbase, 1);
    LOADA(a1, cbase, 1);
    __builtin_amdgcn_s_setprio(1);
    MFMAP(a0, b0);
    MFMAP(a1, b1);
    __builtin_amdgcn_s_setprio(0);
    // end-of-tile: reads must be drained before any wave reaches the next
    // head's restage of this buffer (rule #18: pin after the asm wait).
    asm volatile("s_waitcnt lgkmcnt(0)" ::: "memory");
    __builtin_amdgcn_sched_barrier(0);
    __builtin_amdgcn_s_barrier();

    // ---- per-nt-tile epilogue: threshold filter + rare atomic append ----
    if ((kt & (NKT-1)) == NKT-1){
      const int ntc  = nt0 + (kt >> 3);
      const int colb = ntc*BN + wn*32 + (lane&15);
      const int rowb = mt*BM + wm*64 + ((lane>>4)<<2);
      #pragma unroll
      for (int mf=0; mf<4; mf++){
        #pragma unroll
        for (int nf=0; nf<2; nf++){
          f32x4 a = acc[mf][nf];
          float mx = fmaxf(fmaxf(a[0],a[1]), fmaxf(a[2],a[3]));
          if (mx > TAU_S){
            int colg  = colb + nf*16;
            int rowg0 = rowb + mf*16;
            #pragma unroll
            for (int jj=0; jj<4; jj++){
              if (a[jj] > TAU_S){
                int rowg = rowg0 + jj;
                int pos = atomicAdd(cnt + rowg, 1);
                if (pos < CAP)
                  cand[(size_t)rowg*CAP + pos] = make_float2(a[jj], __int_as_float(colg));
              }
            }
          }
          acc[mf][nf] = zero4;           // reset for next nt-tile
        }
      }
    }
  }
  #undef STAGE_KT
  #undef FOFF
  #undef LOADA
  #undef LOADB
  #undef MFMAP
}

// One block per query: exact rank-select top-64 from candidate list ->
// exact fp64 rescore -> exact top-8 (ties: lower index) -> outputs.
__global__ __launch_bounds__(256) void merge_rescore(const int* __restrict__ cnt,
                                                     const float2* __restrict__ cand,
                                                     const float* __restrict__ q,
                                                     const float* __restrict__ keys,
                                                     const float* __restrict__ values,
                                                     float* __restrict__ out){
  const int qi = blockIdx.x, tid = threadIdx.x;
  const int lane = tid & 63, w = tid >> 6;
  __shared__ __align__(16) float qrow[D_DIM];
  __shared__ __align__(16) float2 ent[CAP];
  __shared__ int    widx[RWIN];
  __shared__ double dsc[RWIN];
  __shared__ double wq[4];
  __shared__ int    fidx[8];
  __shared__ double fsc[8];

  // stage q row + fp64 ||q||^2
  float2 qv = ((const float2*)(q + (size_t)qi*D_DIM))[tid];
  qrow[tid*2] = qv.x; qrow[tid*2+1] = qv.y;
  double pq = (double)qv.x*qv.x + (double)qv.y*qv.y;
  #pragma unroll
  for (int off=32; off>0; off>>=1) pq += __shfl_xor(pq, off);
  if (lane == 0) wq[w] = pq;

  const int n = min(cnt[qi], CAP);
  for (int i = tid; i < n; i += 256) ent[i] = cand[(size_t)qi*CAP + i];
  if (tid < RWIN) widx[tid] = -1;
  __syncthreads();
  double qq = wq[0]+wq[1]+wq[2]+wq[3];

  // exact rank-select: rank under (score desc, col asc); ranks are unique.
  for (int e = tid; e < n; e += 256){
    float se = ent[e].x; int ce = __float_as_int(ent[e].y);
    int rank = 0;
    for (int jx = 0; jx < n; jx++){
      float sj = ent[jx].x; int cj = __float_as_int(ent[jx].y);
      rank += (sj > se) || (sj == se && cj < ce);
    }
    if (rank < RWIN) widx[rank] = ce;
  }
  __syncthreads();

  // exact fp64 rescore: 4 threads per candidate (64 x 4 = 256)
  const int g = tid >> 2, sub = tid & 3;
  const int ki = widx[g];
  const int kis = (ki < 0) ? 0 : ki;
  const float4* kr4 = (const float4*)(keys + (size_t)kis*D_DIM);
  const float4* qr4 = (const float4*)qrow;
  double da = 0.0, dk = 0.0;
  for (int i=0;i<32;i++){
    float4 kv  = kr4[sub*32+i];
    float4 qv4 = qr4[sub*32+i];
    da += (double)qv4.x*kv.x + (double)qv4.y*kv.y + (double)qv4.z*kv.z + (double)qv4.w*kv.w;
    dk += (double)kv.x*kv.x + (double)kv.y*kv.y + (double)kv.z*kv.z + (double)kv.w*kv.w;
  }
  da += __shfl_down(da, 2, 4); da += __shfl_down(da, 1, 4);
  dk += __shfl_down(dk, 2, 4); dk += __shfl_down(dk, 1, 4);
  if (sub == 0){
    double nq = fmax(sqrt(qq), 1e-12);
    double nk = fmax(sqrt(dk), 1e-12);
    dsc[g] = (ki < 0) ? -1e300 : da/(nq*nk);
  }
  __syncthreads();

  if (tid == 0){
    for (int s=0; s<8; s++){
      double bs = -1e301; int bi = 0; int bx = 0x7fffffff;
      for (int c=0; c<RWIN; c++){
        double v = dsc[c]; int ix = widx[c];
        if (v > bs || (v == bs && ix >= 0 && ix < bx)){ bs = v; bi = c; bx = ix; }
      }
      fsc[s] = bs; fidx[s] = (bx == 0x7fffffff) ? 0 : bx;
      dsc[bi] = -1e302;   // remove
    }
  }
  __syncthreads();

  float* out_sc  = out + (size_t)B_Q*K_TOP*V_DIM;
  float* out_idx = out_sc + (size_t)B_Q*K_TOP;
  if (tid < 8){
    out_sc [qi*K_TOP + tid] = (float)fsc[tid];
    out_idx[qi*K_TOP + tid] = (float)fidx[tid];
  }
  #pragma unroll
  for (int s=0; s<8; s++){
    const float2* vr = (const float2*)(values + (size_t)fidx[s]*V_DIM);
    float2* orow = (float2*)(out + ((size_t)qi*K_TOP + s)*V_DIM);
    orow[tid] = vr[tid];
  }
}

extern "C" void kernel_launch(void* const* d_in, const int* in_sizes, int n_in,
                              void* d_out, int out_size, void* d_ws, size_t ws_size,
                              hipStream_t stream){
  const float* q      = (const float*)d_in[0];
  const float* keys   = (const float*)d_in[1];
  const float* values = (const float*)d_in[2];
  unsigned char* ws = (unsigned char*)d_ws;
  uint8_t* qn = (uint8_t*)ws;                                   // 512 KB (fp8)
  uint8_t* kn = qn + (size_t)B_Q*D_DIM;                         // 128 MB (fp8)
  int*    cnt  = (int*)(ws + (size_t)(B_Q + C_K)*D_DIM);        // 4 KB
  float2* cand = (float2*)(ws + (size_t)(B_Q + C_K)*D_DIM + 8192); // 16 MB
  float* out = (float*)d_out;

  hipFuncSetAttribute((const void*)gemm_topk,
                      hipFuncAttributeMaxDynamicSharedMemorySize, 65536);

  nrm_rows<<<dim3(B_Q/4), dim3(256), 0, stream>>>(q, qn, B_Q, cnt, B_Q);
  nrm_rows<<<dim3(C_K/4), dim3(256), 0, stream>>>(keys, kn, C_K, nullptr, 0);
  gemm_topk<<<dim3(512), dim3(512), 32768, stream>>>(qn, kn, cnt, cand);
  merge_rescore<<<dim3(B_Q), dim3(256), 0, stream>>>(cnt, cand, q, keys, values, out);
}

// Round 14
// 461.870 us; speedup vs baseline: 1.0259x; 1.0259x over previous
//
#include <hip/hip_runtime.h>
#include <hip/hip_bf16.h>
#include <stdint.h>

#define B_Q   1024
#define C_K   262144
#define D_DIM 512
#define V_DIM 512
#define K_TOP 8
#define BM 128
#define BN 128
#define BK 64
#define NT (C_K/BN)    /* 2048 n-tiles */
#define MT (B_Q/BM)    /* 8 m-tiles */
#define NKT (D_DIM/BK) /* 8 K-tiles per nt-tile */
#define TPB 32         /* nt-tiles per persistent block (grid 512, 2/CU) */
#define CAP 2048       /* candidate list capacity per query (E[n]~293) */
#define QS 8.0f        /* per-side fp8 pre-scale */
#define TAU_S 8.64f    /* 64 * 0.135 (z=3.05); rescore window 64 -> 13-sigma margin */
#define RWIN 64        /* exact-rescore window */
#define SC1 0x7F7F7F7F /* e8m0 scale bytes = 127 -> 2^0 = 1.0 (exact) */

typedef float f32x4  __attribute__((ext_vector_type(4)));
typedef float f32x16 __attribute__((ext_vector_type(16)));
typedef int   i32x8  __attribute__((ext_vector_type(8)));
typedef __attribute__((address_space(3))) unsigned char lds_uchar;
typedef __attribute__((address_space(1))) const unsigned char gbl_uchar;

// One wave per row: L2-normalize (fp32 norm), scale by QS, emit fp8 e4m3.
// Block 0 additionally zeroes the candidate counters (when cnt != nullptr).
__global__ __launch_bounds__(256) void nrm_rows(const float* __restrict__ in,
                                                uint8_t* __restrict__ out,
                                                int nrows, int* cnt, int ncnt){
  if (cnt != nullptr && blockIdx.x == 0){
    for (int i = threadIdx.x; i < ncnt; i += 256) cnt[i] = 0;
  }
  int row  = blockIdx.x*4 + (threadIdx.x>>6);
  int lane = threadIdx.x & 63;
  if (row >= nrows) return;
  const float4* r4 = (const float4*)(in + (size_t)row*D_DIM);
  float4 a = r4[lane*2], b = r4[lane*2+1];
  float ss = a.x*a.x+a.y*a.y+a.z*a.z+a.w*a.w
           + b.x*b.x+b.y*b.y+b.z*b.z+b.w*b.w;
  #pragma unroll
  for (int off=32; off>0; off>>=1) ss += __shfl_xor(ss, off);
  float rn = QS / fmaxf(sqrtf(ss), 1e-12f);
  int w0 = __builtin_amdgcn_cvt_pk_fp8_f32(a.x*rn, a.y*rn, 0,  false);
  w0     = __builtin_amdgcn_cvt_pk_fp8_f32(a.z*rn, a.w*rn, w0, true);
  int w1 = __builtin_amdgcn_cvt_pk_fp8_f32(b.x*rn, b.y*rn, 0,  false);
  w1     = __builtin_amdgcn_cvt_pk_fp8_f32(b.z*rn, b.w*rn, w1, true);
  ((uint2*)(out + (size_t)row*D_DIM))[lane] = make_uint2((unsigned)w0, (unsigned)w1);
}

// PERSISTENT 128x128 fp8 GEMM via MX-scaled mfma_scale_f32_32x32x64_f8f6f4
// with scale=1.0 (exactly the non-scaled fp8 product, 2.14x the MFMA rate).
// grid=512 = 2 blocks/CU; 8 waves (2Mx4N), each owns 64x32 = two 32x32
// tiles sharing the B fragment: per K-step per wave = 6 ds_read_b128 +
// 2 MFMA (vs 12 b64 + 16 MFMA before). LDS 2 x 16KB double buffer.
// Sync skeleton (R11-R13 proven): head {STAGE(kt+1) -> vmcnt(2) -> publish
// barrier}; end-of-tile {lgkmcnt(0)+sched_barrier -> barrier}. Swizzle: 16B
// unit u' = u ^ ((row>>1)&3) (8-row period matches b128's 8-lane bank
// sweep), linear LDS dest + inverse-swizzled global source.
// Operand layout: A/B row = lane&31, k = (lane>>5)*32 + [0..32) (two 16B
// units); C/D col = lane&31, row = (reg&3)+8*(reg>>2)+4*(lane>>5).
// Epilogue per nt-tile = threshold filter + rare atomic append.
__global__ __launch_bounds__(512, 4) void gemm_topk(const uint8_t* __restrict__ qn,
                                                    const uint8_t* __restrict__ kn,
                                                    int* __restrict__ cnt,
                                                    float2* __restrict__ cand){
  extern __shared__ __align__(16) unsigned char smem[];   // 32768 bytes

  const int tid  = threadIdx.x;
  const int lane = tid & 63;
  const int w    = tid >> 6;           // 0..7
  const int wm = w >> 2, wn = w & 3;   // 2 x 4 wave grid: 128 rows x 128 cols

  const unsigned bid = blockIdx.x;     // 0..511
  const int xcd  = bid & 7;
  const int s    = bid >> 3;           // 0..63
  const int mt   = s & 7;              // 8 m-tiles
  const int nt0  = xcd*256 + (s >> 3)*TPB;   // group walks nt0..nt0+31

  f32x16 acc0 = {0}, acc1 = {0};

  const uint8_t* ab  = qn + (size_t)mt*BM*D_DIM;
  const uint8_t* bb0 = kn + (size_t)nt0*BN*D_DIM;

  // staging map: thread t covers 16B unit t of A and unit t of B (512 each).
  // unit n -> row n>>2, dest-unit n&3; source unit = (n&3) ^ ((row>>1)&3).
  const int srow = tid >> 2;                                  // 0..127
  const unsigned ssw = (unsigned)(((tid & 3) ^ ((srow >> 1) & 3)) << 4);
  const uint8_t* aptr = ab  + (size_t)srow*D_DIM + ssw;       // += 64/K-tile
  const uint8_t* bptr = bb0 + (size_t)srow*D_DIM + ssw;
  const unsigned dst0 = (unsigned)tid*16u;

  #define STAGE_KT(buf_) do{                                                    \
    const unsigned cb_ = (unsigned)(buf_)*16384u;                                \
    __builtin_amdgcn_global_load_lds((gbl_uchar*)(aptr),                         \
        (lds_uchar*)(smem + cb_ + dst0), 16, 0, 0);                              \
    __builtin_amdgcn_global_load_lds((gbl_uchar*)(bptr),                         \
        (lds_uchar*)(smem + cb_ + 8192u + dst0), 16, 0, 0);                      \
  }while(0)

  // byte offset of 16B unit u_ (0..3) within row_: swizzled
  #define UOFF(row_, u_) \
    ((unsigned)((row_)*64 + (((u_) ^ (((row_)>>1)&3))<<4)))

  union frag8 { uint4 q[2]; i32x8 v; };

  STAGE_KT(0);
  aptr += 64; bptr += 64;                // -> K-tile 1 data
  __syncthreads();                       // prologue

  const int kh2 = (lane >> 5) * 2;       // lane's k-half -> first 16B unit
  const int rA0 = wm*64 + (lane & 31);   // A row, tile mh=0
  const int rA1 = rA0 + 32;              // A row, tile mh=1
  const int rB  = wn*32 + (lane & 31);   // B row (= output col)

  for (int kt=0; kt<TPB*NKT; kt++){      // 256 K-tile steps, continuous
    const unsigned cbase = (unsigned)(kt&1)*16384u;

    // loop head (proven): issue STAGE(kt+1), then counted wait — STAGE(kt)'s
    // loads are now older than the 2 newest => landed. Then publish.
    if (kt < TPB*NKT-1){
      STAGE_KT((kt+1)&1);
      const bool wrap = ((kt+1)&7) == 7;   // advance to kt+2's data
      aptr += wrap ? -(7*64) : 64;
      bptr += wrap ? ((size_t)BN*D_DIM - 7*64) : 64;
      asm volatile("s_waitcnt vmcnt(2)" ::: "memory");
    } else {
      asm volatile("s_waitcnt vmcnt(0)" ::: "memory");
    }
    __builtin_amdgcn_sched_barrier(0);
    __builtin_amdgcn_s_barrier();        // publish buffer kt (vmcnt per-wave)

    // body: 6 ds_read_b128 then 2 MFMA — wave-private, compiler-scheduled
    frag8 fa0, fa1, fb;
    fa0.q[0] = *(const uint4*)(smem + cbase + UOFF(rA0, kh2));
    fa0.q[1] = *(const uint4*)(smem + cbase + UOFF(rA0, kh2+1));
    fb.q[0]  = *(const uint4*)(smem + cbase + 8192u + UOFF(rB, kh2));
    fb.q[1]  = *(const uint4*)(smem + cbase + 8192u + UOFF(rB, kh2+1));
    fa1.q[0] = *(const uint4*)(smem + cbase + UOFF(rA1, kh2));
    fa1.q[1] = *(const uint4*)(smem + cbase + UOFF(rA1, kh2+1));
    __builtin_amdgcn_s_setprio(1);
    acc0 = __builtin_amdgcn_mfma_scale_f32_32x32x64_f8f6f4(
               fa0.v, fb.v, acc0, 0, 0, 0, SC1, 0, SC1);
    acc1 = __builtin_amdgcn_mfma_scale_f32_32x32x64_f8f6f4(
               fa1.v, fb.v, acc1, 0, 0, 0, SC1, 0, SC1);
    __builtin_amdgcn_s_setprio(0);
    // end-of-tile: reads must be drained before any wave reaches the next
    // head's restage of this buffer (rule #18: pin after the asm wait).
    asm volatile("s_waitcnt lgkmcnt(0)" ::: "memory");
    __builtin_amdgcn_sched_barrier(0);
    __builtin_amdgcn_s_barrier();

    // ---- per-nt-tile epilogue: threshold filter + rare atomic append ----
    if ((kt & (NKT-1)) == NKT-1){
      const int ntc  = nt0 + (kt >> 3);
      const int colg = ntc*BN + wn*32 + (lane&31);
      #pragma unroll
      for (int mh=0; mh<2; mh++){
        f32x16 a = mh ? acc1 : acc0;     // static selection (rule #20)
        const int rbase = mt*BM + wm*64 + mh*32 + 4*(lane>>5);
        #pragma unroll
        for (int qd=0; qd<4; qd++){
          float v0=a[qd*4+0], v1=a[qd*4+1], v2=a[qd*4+2], v3=a[qd*4+3];
          float mx = fmaxf(fmaxf(v0,v1), fmaxf(v2,v3));
          if (mx > TAU_S){
            #pragma unroll
            for (int jj=0; jj<4; jj++){
              float v = a[qd*4+jj];
              if (v > TAU_S){
                int rowg = rbase + jj + 8*qd;   // (reg&3) + 8*(reg>>2)
                int pos = atomicAdd(cnt + rowg, 1);
                if (pos < CAP)
                  cand[(size_t)rowg*CAP + pos] = make_float2(v, __int_as_float(colg));
              }
            }
          }
        }
      }
      acc0 = (f32x16){0}; acc1 = (f32x16){0};   // reset for next nt-tile
    }
  }
  #undef STAGE_KT
  #undef UOFF
}

// One block per query: exact rank-select top-64 from candidate list ->
// exact fp64 rescore -> exact top-8 (ties: lower index) -> outputs.
__global__ __launch_bounds__(256) void merge_rescore(const int* __restrict__ cnt,
                                                     const float2* __restrict__ cand,
                                                     const float* __restrict__ q,
                                                     const float* __restrict__ keys,
                                                     const float* __restrict__ values,
                                                     float* __restrict__ out){
  const int qi = blockIdx.x, tid = threadIdx.x;
  const int lane = tid & 63, w = tid >> 6;
  __shared__ __align__(16) float qrow[D_DIM];
  __shared__ __align__(16) float2 ent[CAP];
  __shared__ int    widx[RWIN];
  __shared__ double dsc[RWIN];
  __shared__ double wq[4];
  __shared__ int    fidx[8];
  __shared__ double fsc[8];

  // stage q row + fp64 ||q||^2
  float2 qv = ((const float2*)(q + (size_t)qi*D_DIM))[tid];
  qrow[tid*2] = qv.x; qrow[tid*2+1] = qv.y;
  double pq = (double)qv.x*qv.x + (double)qv.y*qv.y;
  #pragma unroll
  for (int off=32; off>0; off>>=1) pq += __shfl_xor(pq, off);
  if (lane == 0) wq[w] = pq;

  const int n = min(cnt[qi], CAP);
  for (int i = tid; i < n; i += 256) ent[i] = cand[(size_t)qi*CAP + i];
  if (tid < RWIN) widx[tid] = -1;
  __syncthreads();
  double qq = wq[0]+wq[1]+wq[2]+wq[3];

  // exact rank-select: rank under (score desc, col asc); ranks are unique.
  for (int e = tid; e < n; e += 256){
    float se = ent[e].x; int ce = __float_as_int(ent[e].y);
    int rank = 0;
    for (int jx = 0; jx < n; jx++){
      float sj = ent[jx].x; int cj = __float_as_int(ent[jx].y);
      rank += (sj > se) || (sj == se && cj < ce);
    }
    if (rank < RWIN) widx[rank] = ce;
  }
  __syncthreads();

  // exact fp64 rescore: 4 threads per candidate (64 x 4 = 256)
  const int g = tid >> 2, sub = tid & 3;
  const int ki = widx[g];
  const int kis = (ki < 0) ? 0 : ki;
  const float4* kr4 = (const float4*)(keys + (size_t)kis*D_DIM);
  const float4* qr4 = (const float4*)qrow;
  double da = 0.0, dk = 0.0;
  for (int i=0;i<32;i++){
    float4 kv  = kr4[sub*32+i];
    float4 qv4 = qr4[sub*32+i];
    da += (double)qv4.x*kv.x + (double)qv4.y*kv.y + (double)qv4.z*kv.z + (double)qv4.w*kv.w;
    dk += (double)kv.x*kv.x + (double)kv.y*kv.y + (double)kv.z*kv.z + (double)kv.w*kv.w;
  }
  da += __shfl_down(da, 2, 4); da += __shfl_down(da, 1, 4);
  dk += __shfl_down(dk, 2, 4); dk += __shfl_down(dk, 1, 4);
  if (sub == 0){
    double nq = fmax(sqrt(qq), 1e-12);
    double nk = fmax(sqrt(dk), 1e-12);
    dsc[g] = (ki < 0) ? -1e300 : da/(nq*nk);
  }
  __syncthreads();

  if (tid == 0){
    for (int s=0; s<8; s++){
      double bs = -1e301; int bi = 0; int bx = 0x7fffffff;
      for (int c=0; c<RWIN; c++){
        double v = dsc[c]; int ix = widx[c];
        if (v > bs || (v == bs && ix >= 0 && ix < bx)){ bs = v; bi = c; bx = ix; }
      }
      fsc[s] = bs; fidx[s] = (bx == 0x7fffffff) ? 0 : bx;
      dsc[bi] = -1e302;   // remove
    }
  }
  __syncthreads();

  float* out_sc  = out + (size_t)B_Q*K_TOP*V_DIM;
  float* out_idx = out_sc + (size_t)B_Q*K_TOP;
  if (tid < 8){
    out_sc [qi*K_TOP + tid] = (float)fsc[tid];
    out_idx[qi*K_TOP + tid] = (float)fidx[tid];
  }
  #pragma unroll
  for (int s=0; s<8; s++){
    const float2* vr = (const float2*)(values + (size_t)fidx[s]*V_DIM);
    float2* orow = (float2*)(out + ((size_t)qi*K_TOP + s)*V_DIM);
    orow[tid] = vr[tid];
  }
}

extern "C" void kernel_launch(void* const* d_in, const int* in_sizes, int n_in,
                              void* d_out, int out_size, void* d_ws, size_t ws_size,
                              hipStream_t stream){
  const float* q      = (const float*)d_in[0];
  const float* keys   = (const float*)d_in[1];
  const float* values = (const float*)d_in[2];
  unsigned char* ws = (unsigned char*)d_ws;
  uint8_t* qn = (uint8_t*)ws;                                   // 512 KB (fp8)
  uint8_t* kn = qn + (size_t)B_Q*D_DIM;                         // 128 MB (fp8)
  int*    cnt  = (int*)(ws + (size_t)(B_Q + C_K)*D_DIM);        // 4 KB
  float2* cand = (float2*)(ws + (size_t)(B_Q + C_K)*D_DIM + 8192); // 16 MB
  float* out = (float*)d_out;

  hipFuncSetAttribute((const void*)gemm_topk,
                      hipFuncAttributeMaxDynamicSharedMemorySize, 65536);

  nrm_rows<<<dim3(B_Q/4), dim3(256), 0, stream>>>(q, qn, B_Q, cnt, B_Q);
  nrm_rows<<<dim3(C_K/4), dim3(256), 0, stream>>>(keys, kn, C_K, nullptr, 0);
  gemm_topk<<<dim3(512), dim3(512), 32768, stream>>>(qn, kn, cnt, cand);
  merge_rescore<<<dim3(B_Q), dim3(256), 0, stream>>>(cnt, cand, q, keys, values, out);
}